// Round 2
// baseline (8563.437 us; speedup 1.0000x reference)
//
#include <hip/hip_runtime.h>

#define N_ROWS  65536
#define K_CB    4096
#define D_MODEL 512
#define TAU     4.0f

typedef __attribute__((ext_vector_type(8))) short bf16x8;
typedef __attribute__((ext_vector_type(4))) float f32x4;
typedef unsigned int   u32;
typedef unsigned short u16;

__device__ __forceinline__ u16 f2bf(float f) {
    u32 u = __float_as_uint(f);
    return (u16)((u + 0x7FFFu + ((u >> 16) & 1u)) >> 16);   // RNE
}

__device__ __forceinline__ void load_lds16(const void* g, void* l) {
    __builtin_amdgcn_global_load_lds(
        (const __attribute__((address_space(1))) u32*)g,
        (__attribute__((address_space(3))) u32*)l, 16, 0, 0);
}

// ---------------- z -> bf16 ----------------
__global__ __launch_bounds__(256) void convert_z(const float* __restrict__ z,
                                                 u16* __restrict__ zbf) {
    size_t i = ((size_t)blockIdx.x * 256 + threadIdx.x) * 8;
    float4 a = *(const float4*)(z + i);
    float4 b = *(const float4*)(z + i + 4);
    ushort4 lo = { f2bf(a.x), f2bf(a.y), f2bf(a.z), f2bf(a.w) };
    ushort4 hi = { f2bf(b.x), f2bf(b.y), f2bf(b.z), f2bf(b.w) };
    *(ushort4*)(zbf + i)     = lo;
    *(ushort4*)(zbf + i + 4) = hi;
}

// ---------------- w -> bf16 + wsq (fp32) + zero fallback counter ----------------
__global__ __launch_bounds__(256) void convert_w(const float* __restrict__ w,
                                                 u16* __restrict__ wbf,
                                                 float* __restrict__ wsq,
                                                 int* __restrict__ counter) {
    if (blockIdx.x == 0 && threadIdx.x == 0) *counter = 0;
    int k    = blockIdx.x * 4 + (threadIdx.x >> 6);
    int lane = threadIdx.x & 63;
    const float4* row = (const float4*)(w + (size_t)k * D_MODEL);
    float s = 0.f;
    #pragma unroll
    for (int c = 0; c < 2; ++c) {
        float4 v = row[lane + 64 * c];
        s += v.x * v.x + v.y * v.y + v.z * v.z + v.w * v.w;
        ushort4 b = { f2bf(v.x), f2bf(v.y), f2bf(v.z), f2bf(v.w) };
        *(ushort4*)(wbf + (size_t)k * D_MODEL + (lane + 64 * c) * 4) = b;
    }
    #pragma unroll
    for (int m = 32; m; m >>= 1) s += __shfl_xor(s, m, 64);
    if (lane == 0) wsq[k] = s;
}

// ---------------- fused bf16-MFMA GEMM + argmin(min1/min2) + gather ----------------
// block: 256 thr = 4 waves, tile 128 rows x (loop over 32 codeword-tiles of 128),
// BK=64 per d-step, global_load_lds(16B) with XOR-swizzled LDS (pre-swizzled source).
__global__ __launch_bounds__(256) void gemm_argmin(
    const u16* __restrict__ zbf, const u16* __restrict__ wbf,
    const float* __restrict__ w, const float* __restrict__ wsq,
    float* __restrict__ out_idx, float* __restrict__ out_q,
    int* __restrict__ list, int* __restrict__ counter) {
    __shared__ u16 As[128 * 64];
    __shared__ u16 Bs[128 * 64];
    __shared__ int idx_s[128];

    const int tid  = threadIdx.x;
    const int lane = tid & 63;
    const int wv   = tid >> 6;
    const int m0   = blockIdx.x * 128;
    const int l15  = lane & 15;
    const int g    = lane >> 4;

    float v1[8], v2[8]; int i1[8];
    #pragma unroll
    for (int i = 0; i < 8; ++i) { v1[i] = 3.4e38f; v2[i] = 3.4e38f; i1[i] = 0; }

    const int srow = lane >> 3;            // row within an 8-row / 1KB chunk
    const int scol = (lane & 7) ^ srow;    // swizzled source 16B-column

    for (int kt = 0; kt < 32; ++kt) {
        f32x4 acc[2][8];
        #pragma unroll
        for (int m = 0; m < 2; ++m)
            #pragma unroll
            for (int n = 0; n < 8; ++n) acc[m][n] = (f32x4){0.f, 0.f, 0.f, 0.f};

        for (int d0 = 0; d0 < D_MODEL; d0 += 64) {
            __syncthreads();
            #pragma unroll
            for (int q = 0; q < 4; ++q) {
                const int ch  = (wv << 2) + q;          // 16 chunks of 1KB per tile
                const int row = (ch << 3) + srow;
                load_lds16(zbf + (size_t)(m0 + row) * D_MODEL + d0 + scol * 8,
                           &As[ch << 9]);
                load_lds16(wbf + (size_t)(kt * 128 + row) * D_MODEL + d0 + scol * 8,
                           &Bs[ch << 9]);
            }
            __syncthreads();

            #pragma unroll
            for (int h = 0; h < 2; ++h) {
                const int colq = (h << 2) + g;          // 16B-col unit (0..7)
                bf16x8 af[2];
                #pragma unroll
                for (int m = 0; m < 2; ++m) {
                    int r = (wv << 5) + (m << 4) + l15;
                    af[m] = *(const bf16x8*)&As[(r << 6) + ((colq ^ (r & 7)) << 3)];
                }
                #pragma unroll
                for (int n = 0; n < 8; ++n) {
                    int r = (n << 4) + l15;
                    bf16x8 bfv = *(const bf16x8*)&Bs[(r << 6) + ((colq ^ (r & 7)) << 3)];
                    #pragma unroll
                    for (int m = 0; m < 2; ++m)
                        acc[m][n] = __builtin_amdgcn_mfma_f32_16x16x32_bf16(
                                        af[m], bfv, acc[m][n], 0, 0, 0);
                }
            }
        }

        // distances s = wsq[k] - 2*dot ; update (min1, idx1, min2); k ascending
        #pragma unroll
        for (int n = 0; n < 8; ++n) {
            int k = (kt << 7) + (n << 4) + l15;
            float wq = wsq[k];
            #pragma unroll
            for (int m = 0; m < 2; ++m)
                #pragma unroll
                for (int r = 0; r < 4; ++r) {
                    float s = fmaf(-2.f, acc[m][n][r], wq);
                    int rs = (m << 2) + r;
                    if (s < v1[rs]) { v2[rs] = v1[rs]; v1[rs] = s; i1[rs] = k; }
                    else if (s < v2[rs]) v2[rs] = s;
                }
        }
    }

    // reduce (min1, idx1, min2) across the 16 column-lanes; first-min tie-break
    #pragma unroll
    for (int rs = 0; rs < 8; ++rs) {
        float a1 = v1[rs], a2 = v2[rs]; int ai = i1[rs];
        #pragma unroll
        for (int off = 1; off < 16; off <<= 1) {
            float b1 = __shfl_xor(a1, off);
            float b2 = __shfl_xor(a2, off);
            int   bi = __shfl_xor(ai, off);
            if (b1 < a1 || (b1 == a1 && bi < ai)) { a2 = fminf(a1, b2); a1 = b1; ai = bi; }
            else                                  { a2 = fminf(a2, b1); }
        }
        if (l15 == 0) {
            int rl = (wv << 5) + ((rs >> 2) << 4) + (g << 2) + (rs & 3);
            out_idx[m0 + rl] = (float)ai;
            idx_s[rl] = ai;
            if (a2 - a1 < TAU) {            // ambiguous under bf16 error -> exact pass
                int p = atomicAdd(counter, 1);
                list[p] = m0 + rl;
            }
        }
    }
    __syncthreads();

    // gather quantized rows (fp32 weight, L2/L3-hot)
    const float4* w4 = (const float4*)w;
    float4* o4 = (float4*)out_q;
    for (int c = tid; c < 128 * 128; c += 256) {
        int r = c >> 7, cc = c & 127;
        o4[(size_t)(m0 + r) * 128 + cc] = w4[(size_t)idx_s[r] * 128 + cc];
    }
}

// ---------------- exact fp32 recompute for ambiguous rows ----------------
// 16 rows per block-iteration, round-1 math (bit-identical accumulation chains).
__global__ __launch_bounds__(256) void exact_fb(
    const float* __restrict__ z, const float* __restrict__ w,
    const float* __restrict__ wsq, const int* __restrict__ list,
    const int* __restrict__ counter,
    float* __restrict__ out_idx, float* __restrict__ out_q) {
    __shared__ float zs[16][36];
    __shared__ float wls[128][36];
    __shared__ int ridx[16];
    __shared__ int best[16];
    const int tid = threadIdx.x;
    const int tx  = tid & 63;
    const int ty  = tid >> 6;
    const int count = *counter;

    for (int base = blockIdx.x * 16; base < count; base += gridDim.x * 16) {
        if (tid < 16) {
            int p = base + tid; if (p > count - 1) p = count - 1;  // pad: duplicate last
            ridx[tid] = list[p];
        }
        __syncthreads();

        float v1[4]; int i1[4];
        #pragma unroll
        for (int i = 0; i < 4; ++i) { v1[i] = 3.4e38f; i1[i] = 0; }

        for (int k0 = 0; k0 < K_CB; k0 += 128) {
            float acc[4][2];
            #pragma unroll
            for (int i = 0; i < 4; ++i) { acc[i][0] = 0.f; acc[i][1] = 0.f; }
            for (int d0 = 0; d0 < D_MODEL; d0 += 32) {
                __syncthreads();
                if (tid < 128) {
                    int r = tid >> 3, cc = tid & 7;
                    *(float4*)&zs[r][cc * 4] =
                        *(const float4*)(z + (size_t)ridx[r] * D_MODEL + d0 + cc * 4);
                }
                #pragma unroll
                for (int i = 0; i < 4; ++i) {
                    int c = tid + 256 * i;
                    int r = c >> 3, cc = c & 7;
                    *(float4*)&wls[r][cc * 4] =
                        *(const float4*)(w + (size_t)(k0 + r) * D_MODEL + d0 + cc * 4);
                }
                __syncthreads();
                #pragma unroll
                for (int d = 0; d < 32; d += 4) {
                    float4 wv0 = *(const float4*)&wls[tx][d];
                    float4 wv1 = *(const float4*)&wls[64 + tx][d];
                    #pragma unroll
                    for (int i = 0; i < 4; ++i) {
                        float4 zv = *(const float4*)&zs[i * 4 + ty][d];
                        acc[i][0] = fmaf(zv.x, wv0.x, acc[i][0]);
                        acc[i][0] = fmaf(zv.y, wv0.y, acc[i][0]);
                        acc[i][0] = fmaf(zv.z, wv0.z, acc[i][0]);
                        acc[i][0] = fmaf(zv.w, wv0.w, acc[i][0]);
                        acc[i][1] = fmaf(zv.x, wv1.x, acc[i][1]);
                        acc[i][1] = fmaf(zv.y, wv1.y, acc[i][1]);
                        acc[i][1] = fmaf(zv.z, wv1.z, acc[i][1]);
                        acc[i][1] = fmaf(zv.w, wv1.w, acc[i][1]);
                    }
                }
            }
            #pragma unroll
            for (int jj = 0; jj < 2; ++jj) {
                int k = k0 + jj * 64 + tx;
                float wq = wsq[k];
                #pragma unroll
                for (int i = 0; i < 4; ++i) {
                    float s = fmaf(-2.f, acc[i][jj], wq);
                    if (s < v1[i]) { v1[i] = s; i1[i] = k; }
                }
            }
        }
        // wave-wide (value, index)-lex argmin: rows r = i*4 + ty
        #pragma unroll
        for (int i = 0; i < 4; ++i) {
            float a1 = v1[i]; int ai = i1[i];
            #pragma unroll
            for (int off = 1; off < 64; off <<= 1) {
                float b1 = __shfl_xor(a1, off);
                int   bi = __shfl_xor(ai, off);
                if (b1 < a1 || (b1 == a1 && bi < ai)) { a1 = b1; ai = bi; }
            }
            if (tx == 0) {
                int r = i * 4 + ty;
                best[r] = ai;
                out_idx[ridx[r]] = (float)ai;
            }
        }
        __syncthreads();
        const float4* w4 = (const float4*)w;
        float4* o4 = (float4*)out_q;
        for (int c = tid; c < 16 * 128; c += 256) {
            int r = c >> 7, cc = c & 127;
            o4[(size_t)ridx[r] * 128 + cc] = w4[(size_t)best[r] * 128 + cc];
        }
        __syncthreads();
    }
}

// ---------------- round-1 fp32 path (safety net if ws too small) ----------------
__global__ __launch_bounds__(256) void wsq_kernel(const float* __restrict__ w,
                                                  float* __restrict__ wsq) {
    int k    = blockIdx.x * 4 + (threadIdx.x >> 6);
    int lane = threadIdx.x & 63;
    const float4* row = (const float4*)(w + (size_t)k * D_MODEL);
    float s = 0.f;
    #pragma unroll
    for (int c = 0; c < 2; ++c) {
        float4 v = row[lane + 64 * c];
        s += v.x * v.x + v.y * v.y + v.z * v.z + v.w * v.w;
    }
    #pragma unroll
    for (int m = 32; m; m >>= 1) s += __shfl_xor(s, m, 64);
    if (lane == 0) wsq[k] = s;
}

__global__ __launch_bounds__(256) void vq_fp32(const float* __restrict__ z,
                                               const float* __restrict__ w,
                                               const float* __restrict__ wsq,
                                               float* __restrict__ out_idx,
                                               float* __restrict__ out_q) {
    __shared__ float zs[64][36];
    __shared__ float ws[128][36];
    __shared__ int   idx_s[64];
    const int tid = threadIdx.x;
    const int tx  = tid & 15;
    const int ty  = tid >> 4;
    const int m0  = blockIdx.x * 64;
    float minv[4]; int mini[4];
    #pragma unroll
    for (int i = 0; i < 4; ++i) { minv[i] = 3.4e38f; mini[i] = 0; }
    for (int k0 = 0; k0 < K_CB; k0 += 128) {
        float acc[4][8];
        #pragma unroll
        for (int i = 0; i < 4; ++i)
            #pragma unroll
            for (int j = 0; j < 8; ++j) acc[i][j] = 0.f;
        for (int d0 = 0; d0 < D_MODEL; d0 += 32) {
            __syncthreads();
            {
                int r = tid >> 3, c = tid & 7;
                #pragma unroll
                for (int it = 0; it < 2; ++it, r += 32)
                    *(float4*)&zs[r][c * 4] = ((const float4*)(z + (size_t)(m0 + r) * D_MODEL + d0))[c];
            }
            {
                int r = tid >> 3, c = tid & 7;
                #pragma unroll
                for (int it = 0; it < 4; ++it, r += 32)
                    *(float4*)&ws[r][c * 4] = ((const float4*)(w + (size_t)(k0 + r) * D_MODEL + d0))[c];
            }
            __syncthreads();
            #pragma unroll
            for (int d = 0; d < 32; d += 4) {
                float4 zv[4];
                #pragma unroll
                for (int i = 0; i < 4; ++i) zv[i] = *(const float4*)&zs[ty * 4 + i][d];
                float4 wv[8];
                #pragma unroll
                for (int j = 0; j < 8; ++j) wv[j] = *(const float4*)&ws[j * 16 + tx][d];
                #pragma unroll
                for (int i = 0; i < 4; ++i)
                    #pragma unroll
                    for (int j = 0; j < 8; ++j) {
                        acc[i][j] = fmaf(zv[i].x, wv[j].x, acc[i][j]);
                        acc[i][j] = fmaf(zv[i].y, wv[j].y, acc[i][j]);
                        acc[i][j] = fmaf(zv[i].z, wv[j].z, acc[i][j]);
                        acc[i][j] = fmaf(zv[i].w, wv[j].w, acc[i][j]);
                    }
            }
        }
        #pragma unroll
        for (int j = 0; j < 8; ++j) {
            int   k  = k0 + j * 16 + tx;
            float wq = wsq[k];
            #pragma unroll
            for (int i = 0; i < 4; ++i) {
                float s = fmaf(-2.f, acc[i][j], wq);
                if (s < minv[i]) { minv[i] = s; mini[i] = k; }
            }
        }
    }
    #pragma unroll
    for (int i = 0; i < 4; ++i) {
        float v = minv[i]; int ix = mini[i];
        #pragma unroll
        for (int m = 8; m; m >>= 1) {
            float ov = __shfl_xor(v, m, 16);
            int   oi = __shfl_xor(ix, m, 16);
            if (ov < v || (ov == v && oi < ix)) { v = ov; ix = oi; }
        }
        if (tx == 0) {
            int row = ty * 4 + i;
            out_idx[m0 + row] = (float)ix;
            idx_s[row] = ix;
        }
    }
    __syncthreads();
    const float4* w4 = (const float4*)w;
    float4*       o4 = (float4*)out_q;
    for (int t = tid; t < 64 * 128; t += 256) {
        int r = t >> 7, c = t & 127;
        o4[(size_t)(m0 + r) * 128 + c] = w4[(size_t)idx_s[r] * 128 + c];
    }
}

extern "C" void kernel_launch(void* const* d_in, const int* in_sizes, int n_in,
                              void* d_out, int out_size, void* d_ws, size_t ws_size,
                              hipStream_t stream) {
    const float* z = (const float*)d_in[0];
    const float* w = (const float*)d_in[1];
    float* out_idx = (float*)d_out;
    float* out_q   = (float*)d_out + N_ROWS;

    // ws layout: [counter 4KB][list 256KB][wsq 16KB][wbf 4MB][zbf 64MB]
    const size_t off_list = 4096;
    const size_t off_wsq  = off_list + (size_t)N_ROWS * 4;        // 266240
    const size_t off_wbf  = off_wsq + (size_t)K_CB * 4;           // 282624
    const size_t off_zbf  = off_wbf + (size_t)K_CB * D_MODEL * 2; // 4476928
    const size_t NEED     = off_zbf + (size_t)N_ROWS * D_MODEL * 2;

    if (ws_size >= NEED) {
        char* ws     = (char*)d_ws;
        int*  counter = (int*)ws;
        int*  list    = (int*)(ws + off_list);
        float* wsq    = (float*)(ws + off_wsq);
        u16*  wbf     = (u16*)(ws + off_wbf);
        u16*  zbf     = (u16*)(ws + off_zbf);

        convert_z<<<(N_ROWS * D_MODEL) / (256 * 8), 256, 0, stream>>>(z, zbf);
        convert_w<<<K_CB / 4, 256, 0, stream>>>(w, wbf, wsq, counter);
        gemm_argmin<<<N_ROWS / 128, 256, 0, stream>>>(zbf, wbf, w, wsq,
                                                      out_idx, out_q, list, counter);
        exact_fb<<<128, 256, 0, stream>>>(z, w, wsq, list, counter, out_idx, out_q);
    } else {
        float* wsq = (float*)d_ws;   // needs only 16 KB
        wsq_kernel<<<K_CB / 4, 256, 0, stream>>>(w, wsq);
        vq_fp32<<<N_ROWS / 64, 256, 0, stream>>>(z, w, wsq, out_idx, out_q);
    }
}

// Round 3
// 1492.510 us; speedup vs baseline: 5.7376x; 5.7376x over previous
//
#include <hip/hip_runtime.h>

#define N_ROWS  65536
#define K_CB    4096
#define D_MODEL 512
#define TAU     0.35f
#define CAPA    8192
#define CAPB    8192

typedef __attribute__((ext_vector_type(8))) _Float16 f16x8;
typedef __attribute__((ext_vector_type(4))) float f32x4;
typedef unsigned int        u32;
typedef unsigned long long  u64;

__device__ __forceinline__ void load_lds16(const void* g, void* l) {
    __builtin_amdgcn_global_load_lds(
        (const __attribute__((address_space(1))) u32*)g,
        (__attribute__((address_space(3))) u32*)l, 16, 0, 0);
}

__device__ __forceinline__ u32 ordf(float f) {
    u32 u = __float_as_uint(f);
    return (u >> 31) ? ~u : (u | 0x80000000u);
}

// ---------------- z -> fp16 ----------------
__global__ __launch_bounds__(256) void convert_z(const float* __restrict__ z,
                                                 _Float16* __restrict__ zh) {
    size_t i = ((size_t)blockIdx.x * 256 + threadIdx.x) * 8;
    float4 a = *(const float4*)(z + i);
    float4 b = *(const float4*)(z + i + 4);
    f16x8 o;
    o[0] = (_Float16)a.x; o[1] = (_Float16)a.y; o[2] = (_Float16)a.z; o[3] = (_Float16)a.w;
    o[4] = (_Float16)b.x; o[5] = (_Float16)b.y; o[6] = (_Float16)b.z; o[7] = (_Float16)b.w;
    *(f16x8*)(zh + i) = o;
}

// ---------------- w -> fp16 + wsq (fp32, validated chain) + zero counters ----------------
__global__ __launch_bounds__(256) void convert_w(const float* __restrict__ w,
                                                 _Float16* __restrict__ wh,
                                                 float* __restrict__ wsq,
                                                 int* __restrict__ counterA,
                                                 int* __restrict__ counterB) {
    if (blockIdx.x == 0 && threadIdx.x == 0) { *counterA = 0; *counterB = 0; }
    int k    = blockIdx.x * 4 + (threadIdx.x >> 6);
    int lane = threadIdx.x & 63;
    const float4* row = (const float4*)(w + (size_t)k * D_MODEL);
    float s = 0.f;
    #pragma unroll
    for (int c = 0; c < 2; ++c) {
        float4 v = row[lane + 64 * c];
        s += v.x * v.x + v.y * v.y + v.z * v.z + v.w * v.w;
        _Float16* o = wh + (size_t)k * D_MODEL + (lane + 64 * c) * 4;
        o[0] = (_Float16)v.x; o[1] = (_Float16)v.y; o[2] = (_Float16)v.z; o[3] = (_Float16)v.w;
    }
    #pragma unroll
    for (int m = 32; m; m >>= 1) s += __shfl_xor(s, m, 64);
    if (lane == 0) wsq[k] = s;
}

// ---------------- fused fp16-MFMA GEMM + top-3 argmin + classify + gather ----------------
__global__ __launch_bounds__(256) void gemm_argmin(
    const _Float16* __restrict__ zh, const _Float16* __restrict__ wh,
    const float* __restrict__ w, const float* __restrict__ wsq,
    float* __restrict__ out_idx, float* __restrict__ out_q,
    int4* __restrict__ listA, int* __restrict__ listB, u64* __restrict__ slots,
    int* __restrict__ counterA, int* __restrict__ counterB) {
    __shared__ _Float16 As[128 * 64];
    __shared__ _Float16 Bs[128 * 64];
    __shared__ int idx_s[128];

    const int tid  = threadIdx.x;
    const int lane = tid & 63;
    const int wv   = tid >> 6;
    const int m0   = blockIdx.x * 128;
    const int l15  = lane & 15;
    const int g    = lane >> 4;

    float v1[8], v2[8], v3[8]; int i1[8], i2[8];
    #pragma unroll
    for (int i = 0; i < 8; ++i) { v1[i] = 3.4e38f; v2[i] = 3.4e38f; v3[i] = 3.4e38f; i1[i] = 0; i2[i] = 0; }

    const int srow = lane >> 3;            // row within an 8-row / 1KB chunk
    const int scol = (lane & 7) ^ srow;    // swizzled source 16B-column

    for (int kt = 0; kt < 32; ++kt) {
        f32x4 acc[2][8];
        #pragma unroll
        for (int m = 0; m < 2; ++m)
            #pragma unroll
            for (int n = 0; n < 8; ++n) acc[m][n] = (f32x4){0.f, 0.f, 0.f, 0.f};

        for (int d0 = 0; d0 < D_MODEL; d0 += 64) {
            __syncthreads();
            #pragma unroll
            for (int q = 0; q < 4; ++q) {
                const int ch  = (wv << 2) + q;          // 16 chunks of 1KB per tile
                const int row = (ch << 3) + srow;
                load_lds16(zh + (size_t)(m0 + row) * D_MODEL + d0 + scol * 8,
                           &As[ch << 9]);
                load_lds16(wh + (size_t)(kt * 128 + row) * D_MODEL + d0 + scol * 8,
                           &Bs[ch << 9]);
            }
            __syncthreads();

            #pragma unroll
            for (int h = 0; h < 2; ++h) {
                const int colq = (h << 2) + g;          // 16B-col unit (0..7)
                f16x8 af[2];
                #pragma unroll
                for (int m = 0; m < 2; ++m) {
                    int r = (wv << 5) + (m << 4) + l15;
                    af[m] = *(const f16x8*)&As[(r << 6) + ((colq ^ (r & 7)) << 3)];
                }
                #pragma unroll
                for (int n = 0; n < 8; ++n) {
                    int r = (n << 4) + l15;
                    f16x8 bv = *(const f16x8*)&Bs[(r << 6) + ((colq ^ (r & 7)) << 3)];
                    #pragma unroll
                    for (int m = 0; m < 2; ++m)
                        acc[m][n] = __builtin_amdgcn_mfma_f32_16x16x32_f16(
                                        af[m], bv, acc[m][n], 0, 0, 0);
                }
            }
        }

        // s = wsq[k] - 2*dot ; guarded top-3 insert, k ascending per lane
        #pragma unroll
        for (int n = 0; n < 8; ++n) {
            int k = (kt << 7) + (n << 4) + l15;
            float wq = wsq[k];
            #pragma unroll
            for (int m = 0; m < 2; ++m)
                #pragma unroll
                for (int r = 0; r < 4; ++r) {
                    float s = fmaf(-2.f, acc[m][n][r], wq);
                    int rs = (m << 2) + r;
                    if (s < v3[rs]) {
                        if (s < v1[rs]) {
                            v3[rs] = v2[rs]; v2[rs] = v1[rs]; i2[rs] = i1[rs];
                            v1[rs] = s; i1[rs] = k;
                        } else if (s < v2[rs]) {
                            v3[rs] = v2[rs]; v2[rs] = s; i2[rs] = k;
                        } else v3[rs] = s;
                    }
                }
        }
    }

    // merge sorted-3 lists across the 16 column-lanes (lex on (value, idx))
    #pragma unroll
    for (int rs = 0; rs < 8; ++rs) {
        float a1 = v1[rs], a2 = v2[rs], a3 = v3[rs];
        int   j1 = i1[rs], j2 = i2[rs];
        #pragma unroll
        for (int off = 1; off < 16; off <<= 1) {
            float b1 = __shfl_xor(a1, off);
            float b2 = __shfl_xor(a2, off);
            float b3 = __shfl_xor(a3, off);
            int   k1 = __shfl_xor(j1, off);
            int   k2 = __shfl_xor(j2, off);
            // insert (b1,k1)
            bool l1 = (b1 < a1) || (b1 == a1 && k1 < j1);
            bool l2 = (b1 < a2) || (b1 == a2 && k1 < j2);
            bool l3 = (b1 < a3);
            if (l1)      { a3 = a2; a2 = a1; j2 = j1; a1 = b1; j1 = k1; }
            else if (l2) { a3 = a2; a2 = b1; j2 = k1; }
            else if (l3) { a3 = b1; }
            // insert (b2,k2) -- cannot beat a1 (b2 lex-greater than b1)
            bool m2 = (b2 < a2) || (b2 == a2 && k2 < j2);
            bool m3 = (b2 < a3);
            if (m2)      { a3 = a2; a2 = b2; j2 = k2; }
            else if (m3) { a3 = b2; }
            // b3 can only land in slot 3
            a3 = fminf(a3, b3);
        }
        if (l15 == 0) {
            int rl = (wv << 5) + ((rs >> 2) << 4) + (g << 2) + (rs & 3);
            int row = m0 + rl;
            out_idx[row] = (float)j1;
            idx_s[rl] = j1;
            float lim = a1 + TAU;
            if (a3 <= lim) {                       // >=3 candidates: full exact scan
                int p = atomicAdd(counterB, 1);
                if (p < CAPB) { listB[p] = row; slots[p] = ~0ull; }
            } else if (a2 <= lim) {                // exactly 2 candidates: pair verify
                int p = atomicAdd(counterA, 1);
                if (p < CAPA) listA[p] = make_int4(row, j1, j2, 0);
                else {
                    int q = atomicAdd(counterB, 1);
                    if (q < CAPB) { listB[q] = row; slots[q] = ~0ull; }
                }
            }
        }
    }
    __syncthreads();

    // gather quantized rows with idx1 (fallback kernels overwrite their rows)
    const float4* w4 = (const float4*)w;
    float4* o4 = (float4*)out_q;
    for (int c = tid; c < 128 * 128; c += 256) {
        int r = c >> 7, cc = c & 127;
        o4[(size_t)(m0 + r) * 128 + cc] = w4[(size_t)idx_s[r] * 128 + cc];
    }
}

// ---------------- exact fp32 pair-verify (one lane per ambiguous row) ----------------
// Accumulation chain is strictly d-ascending single-accumulator fma -- identical
// semantics to the round-1 kernel that matched np on all 65536 rows.
__global__ __launch_bounds__(256) void verify_pairs(
    const float* __restrict__ z, const float* __restrict__ w,
    const float* __restrict__ wsq, const int4* __restrict__ listA,
    const int* __restrict__ counterA,
    float* __restrict__ out_idx, float* __restrict__ out_q) {
    int cA = *counterA; if (cA > CAPA) cA = CAPA;
    for (int e = blockIdx.x * 256 + threadIdx.x; e < cA; e += gridDim.x * 256) {
        int4 ent = listA[e];
        const float4* zr = (const float4*)(z + (size_t)ent.x * D_MODEL);
        const float4* wa = (const float4*)(w + (size_t)ent.y * D_MODEL);
        const float4* wb = (const float4*)(w + (size_t)ent.z * D_MODEL);
        float d1 = 0.f, d2 = 0.f;
        #pragma unroll 8
        for (int c = 0; c < 128; ++c) {
            float4 zv = zr[c];
            float4 a  = wa[c];
            float4 b  = wb[c];
            d1 = fmaf(zv.x, a.x, d1); d1 = fmaf(zv.y, a.y, d1);
            d1 = fmaf(zv.z, a.z, d1); d1 = fmaf(zv.w, a.w, d1);
            d2 = fmaf(zv.x, b.x, d2); d2 = fmaf(zv.y, b.y, d2);
            d2 = fmaf(zv.z, b.z, d2); d2 = fmaf(zv.w, b.w, d2);
        }
        float s1 = fmaf(-2.f, d1, wsq[ent.y]);
        float s2 = fmaf(-2.f, d2, wsq[ent.z]);
        int win = (s2 < s1 || (s2 == s1 && ent.z < ent.y)) ? ent.z : ent.y;
        if (win != ent.y) {
            out_idx[ent.x] = (float)win;
            const float4* src = (const float4*)(w + (size_t)win * D_MODEL);
            float4* dst = (float4*)(out_q + (size_t)ent.x * D_MODEL);
            for (int c = 0; c < 128; ++c) dst[c] = src[c];
        }
    }
}

// ---------------- exact full scan, (row x K/4) work items + packed atomicMin ----------------
__global__ __launch_bounds__(256) void fullscan_part(
    const float* __restrict__ z, const float* __restrict__ w,
    const float* __restrict__ wsq, const int* __restrict__ listB,
    const int* __restrict__ counterB, u64* __restrict__ slots) {
    __shared__ float zs[D_MODEL];
    __shared__ u64 red[4];
    int cB = *counterB; if (cB > CAPB) cB = CAPB;
    int items = cB * 4;
    const int lane = threadIdx.x & 63;
    const int wv   = threadIdx.x >> 6;
    for (int it = blockIdx.x; it < items; it += gridDim.x) {
        int p = it >> 2, q = it & 3;
        int row = listB[p];
        __syncthreads();
        for (int c = threadIdx.x; c < D_MODEL; c += 256) zs[c] = z[(size_t)row * D_MODEL + c];
        __syncthreads();
        int kb = q * 1024 + threadIdx.x * 4;
        const float* wr = w + (size_t)kb * D_MODEL;
        float acc[4] = {0.f, 0.f, 0.f, 0.f};
        for (int c = 0; c < 128; ++c) {
            float4 zv = ((const float4*)zs)[c];
            #pragma unroll
            for (int r = 0; r < 4; ++r) {
                float4 wvv = ((const float4*)(wr + (size_t)r * D_MODEL))[c];
                acc[r] = fmaf(zv.x, wvv.x, acc[r]); acc[r] = fmaf(zv.y, wvv.y, acc[r]);
                acc[r] = fmaf(zv.z, wvv.z, acc[r]); acc[r] = fmaf(zv.w, wvv.w, acc[r]);
            }
        }
        float bv = 3.4e38f; int bi = 0;
        #pragma unroll
        for (int r = 0; r < 4; ++r) {
            float s = fmaf(-2.f, acc[r], wsq[kb + r]);
            if (s < bv) { bv = s; bi = kb + r; }
        }
        u64 key = ((u64)ordf(bv) << 32) | (u32)bi;
        #pragma unroll
        for (int off = 32; off; off >>= 1) {
            u64 o = __shfl_xor(key, off);
            if (o < key) key = o;
        }
        if (lane == 0) red[wv] = key;
        __syncthreads();
        if (threadIdx.x == 0) {
            u64 m = red[0];
            if (red[1] < m) m = red[1];
            if (red[2] < m) m = red[2];
            if (red[3] < m) m = red[3];
            atomicMin(&slots[p], m);
        }
    }
}

__global__ __launch_bounds__(256) void fullscan_final(
    const float* __restrict__ w, const int* __restrict__ listB,
    const int* __restrict__ counterB, const u64* __restrict__ slots,
    float* __restrict__ out_idx, float* __restrict__ out_q) {
    int cB = *counterB; if (cB > CAPB) cB = CAPB;
    const int wv = threadIdx.x >> 6, lane = threadIdx.x & 63;
    for (int p = blockIdx.x * 4 + wv; p < cB; p += gridDim.x * 4) {
        int row = listB[p];
        int win = (int)(u32)(slots[p] & 0xFFFFFFFFull);
        if (lane == 0) out_idx[row] = (float)win;
        const float4* src = (const float4*)(w + (size_t)win * D_MODEL);
        float4* dst = (float4*)(out_q + (size_t)row * D_MODEL);
        dst[lane] = src[lane];
        dst[lane + 64] = src[lane + 64];
    }
}

// ---------------- round-1 fp32 path (safety net if ws too small) ----------------
__global__ __launch_bounds__(256) void wsq_kernel(const float* __restrict__ w,
                                                  float* __restrict__ wsq) {
    int k    = blockIdx.x * 4 + (threadIdx.x >> 6);
    int lane = threadIdx.x & 63;
    const float4* row = (const float4*)(w + (size_t)k * D_MODEL);
    float s = 0.f;
    #pragma unroll
    for (int c = 0; c < 2; ++c) {
        float4 v = row[lane + 64 * c];
        s += v.x * v.x + v.y * v.y + v.z * v.z + v.w * v.w;
    }
    #pragma unroll
    for (int m = 32; m; m >>= 1) s += __shfl_xor(s, m, 64);
    if (lane == 0) wsq[k] = s;
}

__global__ __launch_bounds__(256) void vq_fp32(const float* __restrict__ z,
                                               const float* __restrict__ w,
                                               const float* __restrict__ wsq,
                                               float* __restrict__ out_idx,
                                               float* __restrict__ out_q) {
    __shared__ float zs[64][36];
    __shared__ float ws[128][36];
    __shared__ int   idx_s[64];
    const int tid = threadIdx.x;
    const int tx  = tid & 15;
    const int ty  = tid >> 4;
    const int m0  = blockIdx.x * 64;
    float minv[4]; int mini[4];
    #pragma unroll
    for (int i = 0; i < 4; ++i) { minv[i] = 3.4e38f; mini[i] = 0; }
    for (int k0 = 0; k0 < K_CB; k0 += 128) {
        float acc[4][8];
        #pragma unroll
        for (int i = 0; i < 4; ++i)
            #pragma unroll
            for (int j = 0; j < 8; ++j) acc[i][j] = 0.f;
        for (int d0 = 0; d0 < D_MODEL; d0 += 32) {
            __syncthreads();
            {
                int r = tid >> 3, c = tid & 7;
                #pragma unroll
                for (int it = 0; it < 2; ++it, r += 32)
                    *(float4*)&zs[r][c * 4] = ((const float4*)(z + (size_t)(m0 + r) * D_MODEL + d0))[c];
            }
            {
                int r = tid >> 3, c = tid & 7;
                #pragma unroll
                for (int it = 0; it < 4; ++it, r += 32)
                    *(float4*)&ws[r][c * 4] = ((const float4*)(w + (size_t)(k0 + r) * D_MODEL + d0))[c];
            }
            __syncthreads();
            #pragma unroll
            for (int d = 0; d < 32; d += 4) {
                float4 zv[4];
                #pragma unroll
                for (int i = 0; i < 4; ++i) zv[i] = *(const float4*)&zs[ty * 4 + i][d];
                float4 wv[8];
                #pragma unroll
                for (int j = 0; j < 8; ++j) wv[j] = *(const float4*)&ws[j * 16 + tx][d];
                #pragma unroll
                for (int i = 0; i < 4; ++i)
                    #pragma unroll
                    for (int j = 0; j < 8; ++j) {
                        acc[i][j] = fmaf(zv[i].x, wv[j].x, acc[i][j]);
                        acc[i][j] = fmaf(zv[i].y, wv[j].y, acc[i][j]);
                        acc[i][j] = fmaf(zv[i].z, wv[j].z, acc[i][j]);
                        acc[i][j] = fmaf(zv[i].w, wv[j].w, acc[i][j]);
                    }
            }
        }
        #pragma unroll
        for (int j = 0; j < 8; ++j) {
            int   k  = k0 + j * 16 + tx;
            float wq = wsq[k];
            #pragma unroll
            for (int i = 0; i < 4; ++i) {
                float s = fmaf(-2.f, acc[i][j], wq);
                if (s < minv[i]) { minv[i] = s; mini[i] = k; }
            }
        }
    }
    #pragma unroll
    for (int i = 0; i < 4; ++i) {
        float v = minv[i]; int ix = mini[i];
        #pragma unroll
        for (int m = 8; m; m >>= 1) {
            float ov = __shfl_xor(v, m, 16);
            int   oi = __shfl_xor(ix, m, 16);
            if (ov < v || (ov == v && oi < ix)) { v = ov; ix = oi; }
        }
        if (tx == 0) {
            int row = ty * 4 + i;
            out_idx[m0 + row] = (float)ix;
            idx_s[row] = ix;
        }
    }
    __syncthreads();
    const float4* w4 = (const float4*)w;
    float4*       o4 = (float4*)out_q;
    for (int t = tid; t < 64 * 128; t += 256) {
        int r = t >> 7, c = t & 127;
        o4[(size_t)(m0 + r) * 128 + c] = w4[(size_t)idx_s[r] * 128 + c];
    }
}

extern "C" void kernel_launch(void* const* d_in, const int* in_sizes, int n_in,
                              void* d_out, int out_size, void* d_ws, size_t ws_size,
                              hipStream_t stream) {
    const float* z = (const float*)d_in[0];
    const float* w = (const float*)d_in[1];
    float* out_idx = (float*)d_out;
    float* out_q   = (float*)d_out + N_ROWS;

    // ws layout (16B-aligned pieces):
    // [counters 256][listA int4 x 8192][listB int x 8192][slots u64 x 8192]
    // [wsq 16KB][wh fp16 4MB][zh fp16 64MB]   total = 71,549,184 bytes
    const size_t off_listA = 256;
    const size_t off_listB = off_listA + (size_t)CAPA * 16;            // 131328
    const size_t off_slots = off_listB + (size_t)CAPB * 4;             // 164096
    const size_t off_wsq   = off_slots + (size_t)CAPB * 8;             // 229632
    const size_t off_wh    = off_wsq + (size_t)K_CB * 4;               // 246016
    const size_t off_zh    = off_wh + (size_t)K_CB * D_MODEL * 2;      // 4440320
    const size_t NEED      = off_zh + (size_t)N_ROWS * D_MODEL * 2;    // 71549184

    if (ws_size >= NEED) {
        char* ws = (char*)d_ws;
        int*  counterA = (int*)ws;
        int*  counterB = (int*)(ws + 4);
        int4* listA    = (int4*)(ws + off_listA);
        int*  listB    = (int*)(ws + off_listB);
        u64*  slots    = (u64*)(ws + off_slots);
        float* wsq     = (float*)(ws + off_wsq);
        _Float16* wh   = (_Float16*)(ws + off_wh);
        _Float16* zh   = (_Float16*)(ws + off_zh);

        convert_z<<<(N_ROWS * D_MODEL) / (256 * 8), 256, 0, stream>>>(z, zh);
        convert_w<<<K_CB / 4, 256, 0, stream>>>(w, wh, wsq, counterA, counterB);
        gemm_argmin<<<N_ROWS / 128, 256, 0, stream>>>(zh, wh, w, wsq, out_idx, out_q,
                                                      listA, listB, slots,
                                                      counterA, counterB);
        verify_pairs<<<64, 256, 0, stream>>>(z, w, wsq, listA, counterA, out_idx, out_q);
        fullscan_part<<<512, 256, 0, stream>>>(z, w, wsq, listB, counterB, slots);
        fullscan_final<<<64, 256, 0, stream>>>(w, listB, counterB, slots, out_idx, out_q);
    } else {
        float* wsq = (float*)d_ws;   // needs only 16 KB
        wsq_kernel<<<K_CB / 4, 256, 0, stream>>>(w, wsq);
        vq_fp32<<<N_ROWS / 64, 256, 0, stream>>>(z, w, wsq, out_idx, out_q);
    }
}

// Round 4
// 773.656 us; speedup vs baseline: 11.0688x; 1.9292x over previous
//
#include <hip/hip_runtime.h>

#define N_ROWS  65536
#define K_CB    4096
#define D_MODEL 512
#define TAU     0.35f
#define CAPA    8192
#define CAPB    8192

typedef __attribute__((ext_vector_type(8))) _Float16 f16x8;
typedef __attribute__((ext_vector_type(4))) float f32x4;
typedef unsigned int        u32;
typedef unsigned long long  u64;

__device__ __forceinline__ void load_lds16(const void* g, void* l) {
    __builtin_amdgcn_global_load_lds(
        (const __attribute__((address_space(1))) u32*)g,
        (__attribute__((address_space(3))) u32*)l, 16, 0, 0);
}

__device__ __forceinline__ u32 ordf(float f) {
    u32 u = __float_as_uint(f);
    return (u >> 31) ? ~u : (u | 0x80000000u);
}

// ---------------- z -> fp16 ----------------
__global__ __launch_bounds__(256) void convert_z(const float* __restrict__ z,
                                                 _Float16* __restrict__ zh) {
    size_t i = ((size_t)blockIdx.x * 256 + threadIdx.x) * 8;
    float4 a = *(const float4*)(z + i);
    float4 b = *(const float4*)(z + i + 4);
    f16x8 o;
    o[0] = (_Float16)a.x; o[1] = (_Float16)a.y; o[2] = (_Float16)a.z; o[3] = (_Float16)a.w;
    o[4] = (_Float16)b.x; o[5] = (_Float16)b.y; o[6] = (_Float16)b.z; o[7] = (_Float16)b.w;
    *(f16x8*)(zh + i) = o;
}

// ---------------- w -> fp16 + wsq (fp32, validated chain) + zero counters ----------------
__global__ __launch_bounds__(256) void convert_w(const float* __restrict__ w,
                                                 _Float16* __restrict__ wh,
                                                 float* __restrict__ wsq,
                                                 int* __restrict__ counterA,
                                                 int* __restrict__ counterB) {
    if (blockIdx.x == 0 && threadIdx.x == 0) { *counterA = 0; *counterB = 0; }
    int k    = blockIdx.x * 4 + (threadIdx.x >> 6);
    int lane = threadIdx.x & 63;
    const float4* row = (const float4*)(w + (size_t)k * D_MODEL);
    float s = 0.f;
    #pragma unroll
    for (int c = 0; c < 2; ++c) {
        float4 v = row[lane + 64 * c];
        s += v.x * v.x + v.y * v.y + v.z * v.z + v.w * v.w;
        _Float16* o = wh + (size_t)k * D_MODEL + (lane + 64 * c) * 4;
        o[0] = (_Float16)v.x; o[1] = (_Float16)v.y; o[2] = (_Float16)v.z; o[3] = (_Float16)v.w;
    }
    #pragma unroll
    for (int m = 32; m; m >>= 1) s += __shfl_xor(s, m, 64);
    if (lane == 0) wsq[k] = s;
}

// ---------------- fused fp16-MFMA GEMM + top-3 argmin + classify + gather ----------------
// BM=64 rows/block, 32 kt-tiles of 128 cols, BK=64, double-buffered LDS,
// flattened 256-chunk pipeline with counted vmcnt(6) + raw barriers.
__global__ __launch_bounds__(256, 3) void gemm_argmin(
    const _Float16* __restrict__ zh, const _Float16* __restrict__ wh,
    const float* __restrict__ w, const float* __restrict__ wsq,
    float* __restrict__ out_idx, float* __restrict__ out_q,
    int4* __restrict__ listA, int* __restrict__ listB, u64* __restrict__ slots,
    int* __restrict__ counterA, int* __restrict__ counterB) {
    __shared__ _Float16 As[2][64 * 64];     // 2 x 8KB
    __shared__ _Float16 Bs[2][128 * 64];    // 2 x 16KB
    __shared__ int idx_s[64];

    const int tid  = threadIdx.x;
    const int lane = tid & 63;
    const int wv   = tid >> 6;
    const int m0   = blockIdx.x * 64;
    const int l15  = lane & 15;
    const int g    = lane >> 4;

    const int srow = lane >> 3;            // row within an 8-row / 1KB chunk
    const int scol = (lane & 7) ^ srow;    // pre-swizzled source 16B-column

    float v1[4], v2[4], v3[4]; int i1[4], i2[4];
    #pragma unroll
    for (int i = 0; i < 4; ++i) { v1[i] = 3.4e38f; v2[i] = 3.4e38f; v3[i] = 3.4e38f; i1[i] = 0; i2[i] = 0; }

    // stage chunk (kts, d0s) into buffer b: 6 global_load_lds per wave
    auto STAGE = [&](int kts, int d0s, int b) {
        const int chA = wv << 1;                       // 2 A-chunks per wave
        const _Float16* as = zh + (size_t)(m0 + (chA << 3) + srow) * D_MODEL + d0s + scol * 8;
        load_lds16(as,                      &As[b][chA << 9]);
        load_lds16(as + (size_t)8 * D_MODEL, &As[b][(chA + 1) << 9]);
        const int chB = wv << 2;                       // 4 B-chunks per wave
        const _Float16* bs = wh + (size_t)(kts * 128 + (chB << 3) + srow) * D_MODEL + d0s + scol * 8;
        #pragma unroll
        for (int q = 0; q < 4; ++q)
            load_lds16(bs + (size_t)(q * 8) * D_MODEL, &Bs[b][(chB + q) << 9]);
    };

    STAGE(0, 0, 0);                                    // prologue: chunk 0 -> buf 0

    for (int kt = 0; kt < 32; ++kt) {
        f32x4 acc[8];
        float wq[8];
        #pragma unroll
        for (int dc = 0; dc < 8; ++dc) {
            const int cur = dc & 1;
            // ---- issue next chunk's stage (skip only after the very last chunk)
            if (dc < 7) {
                STAGE(kt, (dc + 1) << 6, cur ^ 1);
                asm volatile("s_waitcnt vmcnt(6)" ::: "memory");
            } else if (kt < 31) {
                STAGE(kt + 1, 0, cur ^ 1);
                asm volatile("s_waitcnt vmcnt(6)" ::: "memory");
            } else {
                asm volatile("s_waitcnt vmcnt(0)" ::: "memory");
            }
            __builtin_amdgcn_s_barrier();              // current chunk visible to all waves
            __builtin_amdgcn_sched_barrier(0);

            if (dc == 0) {
                #pragma unroll
                for (int n = 0; n < 8; ++n) {
                    acc[n] = (f32x4){0.f, 0.f, 0.f, 0.f};
                    wq[n] = wsq[(kt << 7) + (n << 4) + l15];
                }
            }

            // ---- compute: wave tile 16 rows x 128 cols, 16 MFMA
            #pragma unroll
            for (int h = 0; h < 2; ++h) {
                const int colq = (h << 2) + g;         // 16B-col unit (0..7)
                const int ar = (wv << 4) + l15;
                f16x8 af = *(const f16x8*)&As[cur][(ar << 6) + ((colq ^ (ar & 7)) << 3)];
                #pragma unroll
                for (int n = 0; n < 8; ++n) {
                    const int br = (n << 4) + l15;
                    f16x8 bv = *(const f16x8*)&Bs[cur][(br << 6) + ((colq ^ (br & 7)) << 3)];
                    acc[n] = __builtin_amdgcn_mfma_f32_16x16x32_f16(af, bv, acc[n], 0, 0, 0);
                }
            }

            // ---- kt epilogue: registers only (wq preloaded)
            if (dc == 7) {
                #pragma unroll
                for (int n = 0; n < 8; ++n) {
                    int k = (kt << 7) + (n << 4) + l15;
                    #pragma unroll
                    for (int r = 0; r < 4; ++r) {
                        float s = fmaf(-2.f, acc[n][r], wq[n]);
                        if (s < v3[r]) {
                            if (s < v1[r]) {
                                v3[r] = v2[r]; v2[r] = v1[r]; i2[r] = i1[r];
                                v1[r] = s; i1[r] = k;
                            } else if (s < v2[r]) {
                                v3[r] = v2[r]; v2[r] = s; i2[r] = k;
                            } else v3[r] = s;
                        }
                    }
                }
            }
            __builtin_amdgcn_sched_barrier(0);
            __builtin_amdgcn_s_barrier();              // all waves done reading buf[cur]
        }
    }

    // merge sorted-3 lists across the 16 column-lanes (lex on (value, idx))
    #pragma unroll
    for (int rs = 0; rs < 4; ++rs) {
        float a1 = v1[rs], a2 = v2[rs], a3 = v3[rs];
        int   j1 = i1[rs], j2 = i2[rs];
        #pragma unroll
        for (int off = 1; off < 16; off <<= 1) {
            float b1 = __shfl_xor(a1, off);
            float b2 = __shfl_xor(a2, off);
            float b3 = __shfl_xor(a3, off);
            int   k1 = __shfl_xor(j1, off);
            int   k2 = __shfl_xor(j2, off);
            bool l1 = (b1 < a1) || (b1 == a1 && k1 < j1);
            bool l2 = (b1 < a2) || (b1 == a2 && k1 < j2);
            bool l3 = (b1 < a3);
            if (l1)      { a3 = a2; a2 = a1; j2 = j1; a1 = b1; j1 = k1; }
            else if (l2) { a3 = a2; a2 = b1; j2 = k1; }
            else if (l3) { a3 = b1; }
            bool m2 = (b2 < a2) || (b2 == a2 && k2 < j2);
            bool m3 = (b2 < a3);
            if (m2)      { a3 = a2; a2 = b2; j2 = k2; }
            else if (m3) { a3 = b2; }
            a3 = fminf(a3, b3);
        }
        if (l15 == 0) {
            int rl = (wv << 4) + (g << 2) + rs;
            int row = m0 + rl;
            out_idx[row] = (float)j1;
            idx_s[rl] = j1;
            float lim = a1 + TAU;
            if (a3 <= lim) {                       // >=3 candidates: full exact scan
                int p = atomicAdd(counterB, 1);
                if (p < CAPB) { listB[p] = row; slots[p] = ~0ull; }
            } else if (a2 <= lim) {                // exactly 2 candidates: pair verify
                int p = atomicAdd(counterA, 1);
                if (p < CAPA) listA[p] = make_int4(row, j1, j2, 0);
                else {
                    int q = atomicAdd(counterB, 1);
                    if (q < CAPB) { listB[q] = row; slots[q] = ~0ull; }
                }
            }
        }
    }
    __syncthreads();

    // gather quantized rows with idx1 (fallback kernels overwrite their rows)
    const float4* w4 = (const float4*)w;
    float4* o4 = (float4*)out_q;
    for (int c = tid; c < 64 * 128; c += 256) {
        int r = c >> 7, cc = c & 127;
        o4[(size_t)(m0 + r) * 128 + cc] = w4[(size_t)idx_s[r] * 128 + cc];
    }
}

// ---------------- exact fp32 pair-verify (one lane per ambiguous row) ----------------
__global__ __launch_bounds__(256) void verify_pairs(
    const float* __restrict__ z, const float* __restrict__ w,
    const float* __restrict__ wsq, const int4* __restrict__ listA,
    const int* __restrict__ counterA,
    float* __restrict__ out_idx, float* __restrict__ out_q) {
    int cA = *counterA; if (cA > CAPA) cA = CAPA;
    for (int e = blockIdx.x * 256 + threadIdx.x; e < cA; e += gridDim.x * 256) {
        int4 ent = listA[e];
        const float4* zr = (const float4*)(z + (size_t)ent.x * D_MODEL);
        const float4* wa = (const float4*)(w + (size_t)ent.y * D_MODEL);
        const float4* wb = (const float4*)(w + (size_t)ent.z * D_MODEL);
        float d1 = 0.f, d2 = 0.f;
        #pragma unroll 8
        for (int c = 0; c < 128; ++c) {
            float4 zv = zr[c];
            float4 a  = wa[c];
            float4 b  = wb[c];
            d1 = fmaf(zv.x, a.x, d1); d1 = fmaf(zv.y, a.y, d1);
            d1 = fmaf(zv.z, a.z, d1); d1 = fmaf(zv.w, a.w, d1);
            d2 = fmaf(zv.x, b.x, d2); d2 = fmaf(zv.y, b.y, d2);
            d2 = fmaf(zv.z, b.z, d2); d2 = fmaf(zv.w, b.w, d2);
        }
        float s1 = fmaf(-2.f, d1, wsq[ent.y]);
        float s2 = fmaf(-2.f, d2, wsq[ent.z]);
        int win = (s2 < s1 || (s2 == s1 && ent.z < ent.y)) ? ent.z : ent.y;
        if (win != ent.y) {
            out_idx[ent.x] = (float)win;
            const float4* src = (const float4*)(w + (size_t)win * D_MODEL);
            float4* dst = (float4*)(out_q + (size_t)ent.x * D_MODEL);
            for (int c = 0; c < 128; ++c) dst[c] = src[c];
        }
    }
}

// ---------------- exact full scan, (row x K/4) work items + packed atomicMin ----------------
__global__ __launch_bounds__(256) void fullscan_part(
    const float* __restrict__ z, const float* __restrict__ w,
    const float* __restrict__ wsq, const int* __restrict__ listB,
    const int* __restrict__ counterB, u64* __restrict__ slots) {
    __shared__ float zs[D_MODEL];
    __shared__ u64 red[4];
    int cB = *counterB; if (cB > CAPB) cB = CAPB;
    int items = cB * 4;
    const int lane = threadIdx.x & 63;
    const int wv   = threadIdx.x >> 6;
    for (int it = blockIdx.x; it < items; it += gridDim.x) {
        int p = it >> 2, q = it & 3;
        int row = listB[p];
        __syncthreads();
        for (int c = threadIdx.x; c < D_MODEL; c += 256) zs[c] = z[(size_t)row * D_MODEL + c];
        __syncthreads();
        int kb = q * 1024 + threadIdx.x * 4;
        const float* wr = w + (size_t)kb * D_MODEL;
        float acc[4] = {0.f, 0.f, 0.f, 0.f};
        for (int c = 0; c < 128; ++c) {
            float4 zv = ((const float4*)zs)[c];
            #pragma unroll
            for (int r = 0; r < 4; ++r) {
                float4 wvv = ((const float4*)(wr + (size_t)r * D_MODEL))[c];
                acc[r] = fmaf(zv.x, wvv.x, acc[r]); acc[r] = fmaf(zv.y, wvv.y, acc[r]);
                acc[r] = fmaf(zv.z, wvv.z, acc[r]); acc[r] = fmaf(zv.w, wvv.w, acc[r]);
            }
        }
        float bv = 3.4e38f; int bi = 0;
        #pragma unroll
        for (int r = 0; r < 4; ++r) {
            float s = fmaf(-2.f, acc[r], wsq[kb + r]);
            if (s < bv) { bv = s; bi = kb + r; }
        }
        u64 key = ((u64)ordf(bv) << 32) | (u32)bi;
        #pragma unroll
        for (int off = 32; off; off >>= 1) {
            u64 o = __shfl_xor(key, off);
            if (o < key) key = o;
        }
        if (lane == 0) red[wv] = key;
        __syncthreads();
        if (threadIdx.x == 0) {
            u64 m = red[0];
            if (red[1] < m) m = red[1];
            if (red[2] < m) m = red[2];
            if (red[3] < m) m = red[3];
            atomicMin(&slots[p], m);
        }
    }
}

__global__ __launch_bounds__(256) void fullscan_final(
    const float* __restrict__ w, const int* __restrict__ listB,
    const int* __restrict__ counterB, const u64* __restrict__ slots,
    float* __restrict__ out_idx, float* __restrict__ out_q) {
    int cB = *counterB; if (cB > CAPB) cB = CAPB;
    const int wv = threadIdx.x >> 6, lane = threadIdx.x & 63;
    for (int p = blockIdx.x * 4 + wv; p < cB; p += gridDim.x * 4) {
        int row = listB[p];
        int win = (int)(u32)(slots[p] & 0xFFFFFFFFull);
        if (lane == 0) out_idx[row] = (float)win;
        const float4* src = (const float4*)(w + (size_t)win * D_MODEL);
        float4* dst = (float4*)(out_q + (size_t)row * D_MODEL);
        dst[lane] = src[lane];
        dst[lane + 64] = src[lane + 64];
    }
}

// ---------------- round-1 fp32 path (safety net if ws too small) ----------------
__global__ __launch_bounds__(256) void wsq_kernel(const float* __restrict__ w,
                                                  float* __restrict__ wsq) {
    int k    = blockIdx.x * 4 + (threadIdx.x >> 6);
    int lane = threadIdx.x & 63;
    const float4* row = (const float4*)(w + (size_t)k * D_MODEL);
    float s = 0.f;
    #pragma unroll
    for (int c = 0; c < 2; ++c) {
        float4 v = row[lane + 64 * c];
        s += v.x * v.x + v.y * v.y + v.z * v.z + v.w * v.w;
    }
    #pragma unroll
    for (int m = 32; m; m >>= 1) s += __shfl_xor(s, m, 64);
    if (lane == 0) wsq[k] = s;
}

__global__ __launch_bounds__(256) void vq_fp32(const float* __restrict__ z,
                                               const float* __restrict__ w,
                                               const float* __restrict__ wsq,
                                               float* __restrict__ out_idx,
                                               float* __restrict__ out_q) {
    __shared__ float zs[64][36];
    __shared__ float ws[128][36];
    __shared__ int   idx_s[64];
    const int tid = threadIdx.x;
    const int tx  = tid & 15;
    const int ty  = tid >> 4;
    const int m0  = blockIdx.x * 64;
    float minv[4]; int mini[4];
    #pragma unroll
    for (int i = 0; i < 4; ++i) { minv[i] = 3.4e38f; mini[i] = 0; }
    for (int k0 = 0; k0 < K_CB; k0 += 128) {
        float acc[4][8];
        #pragma unroll
        for (int i = 0; i < 4; ++i)
            #pragma unroll
            for (int j = 0; j < 8; ++j) acc[i][j] = 0.f;
        for (int d0 = 0; d0 < D_MODEL; d0 += 32) {
            __syncthreads();
            {
                int r = tid >> 3, c = tid & 7;
                #pragma unroll
                for (int it = 0; it < 2; ++it, r += 32)
                    *(float4*)&zs[r][c * 4] = ((const float4*)(z + (size_t)(m0 + r) * D_MODEL + d0))[c];
            }
            {
                int r = tid >> 3, c = tid & 7;
                #pragma unroll
                for (int it = 0; it < 4; ++it, r += 32)
                    *(float4*)&ws[r][c * 4] = ((const float4*)(w + (size_t)(k0 + r) * D_MODEL + d0))[c];
            }
            __syncthreads();
            #pragma unroll
            for (int d = 0; d < 32; d += 4) {
                float4 zv[4];
                #pragma unroll
                for (int i = 0; i < 4; ++i) zv[i] = *(const float4*)&zs[ty * 4 + i][d];
                float4 wv[8];
                #pragma unroll
                for (int j = 0; j < 8; ++j) wv[j] = *(const float4*)&ws[j * 16 + tx][d];
                #pragma unroll
                for (int i = 0; i < 4; ++i)
                    #pragma unroll
                    for (int j = 0; j < 8; ++j) {
                        acc[i][j] = fmaf(zv[i].x, wv[j].x, acc[i][j]);
                        acc[i][j] = fmaf(zv[i].y, wv[j].y, acc[i][j]);
                        acc[i][j] = fmaf(zv[i].z, wv[j].z, acc[i][j]);
                        acc[i][j] = fmaf(zv[i].w, wv[j].w, acc[i][j]);
                    }
            }
        }
        #pragma unroll
        for (int j = 0; j < 8; ++j) {
            int   k  = k0 + j * 16 + tx;
            float wq = wsq[k];
            #pragma unroll
            for (int i = 0; i < 4; ++i) {
                float s = fmaf(-2.f, acc[i][j], wq);
                if (s < minv[i]) { minv[i] = s; mini[i] = k; }
            }
        }
    }
    #pragma unroll
    for (int i = 0; i < 4; ++i) {
        float v = minv[i]; int ix = mini[i];
        #pragma unroll
        for (int m = 8; m; m >>= 1) {
            float ov = __shfl_xor(v, m, 16);
            int   oi = __shfl_xor(ix, m, 16);
            if (ov < v || (ov == v && oi < ix)) { v = ov; ix = oi; }
        }
        if (tx == 0) {
            int row = ty * 4 + i;
            out_idx[m0 + row] = (float)ix;
            idx_s[row] = ix;
        }
    }
    __syncthreads();
    const float4* w4 = (const float4*)w;
    float4*       o4 = (float4*)out_q;
    for (int t = tid; t < 64 * 128; t += 256) {
        int r = t >> 7, c = t & 127;
        o4[(size_t)(m0 + r) * 128 + c] = w4[(size_t)idx_s[r] * 128 + c];
    }
}

extern "C" void kernel_launch(void* const* d_in, const int* in_sizes, int n_in,
                              void* d_out, int out_size, void* d_ws, size_t ws_size,
                              hipStream_t stream) {
    const float* z = (const float*)d_in[0];
    const float* w = (const float*)d_in[1];
    float* out_idx = (float*)d_out;
    float* out_q   = (float*)d_out + N_ROWS;

    const size_t off_listA = 256;
    const size_t off_listB = off_listA + (size_t)CAPA * 16;
    const size_t off_slots = off_listB + (size_t)CAPB * 4;
    const size_t off_wsq   = off_slots + (size_t)CAPB * 8;
    const size_t off_wh    = off_wsq + (size_t)K_CB * 4;
    const size_t off_zh    = off_wh + (size_t)K_CB * D_MODEL * 2;
    const size_t NEED      = off_zh + (size_t)N_ROWS * D_MODEL * 2;

    if (ws_size >= NEED) {
        char* ws = (char*)d_ws;
        int*  counterA = (int*)ws;
        int*  counterB = (int*)(ws + 4);
        int4* listA    = (int4*)(ws + off_listA);
        int*  listB    = (int*)(ws + off_listB);
        u64*  slots    = (u64*)(ws + off_slots);
        float* wsq     = (float*)(ws + off_wsq);
        _Float16* wh   = (_Float16*)(ws + off_wh);
        _Float16* zh   = (_Float16*)(ws + off_zh);

        convert_z<<<(N_ROWS * D_MODEL) / (256 * 8), 256, 0, stream>>>(z, zh);
        convert_w<<<K_CB / 4, 256, 0, stream>>>(w, wh, wsq, counterA, counterB);
        gemm_argmin<<<N_ROWS / 64, 256, 0, stream>>>(zh, wh, w, wsq, out_idx, out_q,
                                                     listA, listB, slots,
                                                     counterA, counterB);
        verify_pairs<<<64, 256, 0, stream>>>(z, w, wsq, listA, counterA, out_idx, out_q);
        fullscan_part<<<512, 256, 0, stream>>>(z, w, wsq, listB, counterB, slots);
        fullscan_final<<<64, 256, 0, stream>>>(w, listB, counterB, slots, out_idx, out_q);
    } else {
        float* wsq = (float*)d_ws;
        wsq_kernel<<<K_CB / 4, 256, 0, stream>>>(w, wsq);
        vq_fp32<<<N_ROWS / 64, 256, 0, stream>>>(z, w, wsq, out_idx, out_q);
    }
}